// Round 12
// baseline (45.712 us; speedup 1.0000x reference)
//
#include <hip/hip_runtime.h>

// Kuramoto helix network v13: halve the waves, not the work.
// v12 post-mortem: dynamics is LDS-READ-INSTRUCTION bound: every wave reads
// the full A (8KB) per step; 16 waves x 8 ds_read_b128 = 128 instr x ~12cyc
// ~= 1536 cyc/step (matches measured ~1680). Fix: 512-thr block, 8 waves x
// 2 col-tiles (Bf[2][8]=64 VGPR), 8 rows full-M, grid 256 -> 64 read-instr
// ~= 768 cyc/step; MFMA/CU/step unchanged (128). At 2 waves/SIMD the VGPR
// cap is 256 -> K dbuf affordable (BfA+BfB=128+~70 work). Keeps v12's raw
// barriers (no vmcnt drain), setprio, split accumulators.

#define NB 2048
#define NIN 512
#define NOUT 128
#define NOSC 256
#define DTT 0.1f

#define WS_WENC (512*1024)
#define WS_WD   (1024*1024)

typedef _Float16 f16;
typedef _Float16 f16x8 __attribute__((ext_vector_type(8)));
typedef float f32x4 __attribute__((ext_vector_type(4)));

__device__ __forceinline__ float wrapf(float t) {
    return t - 6.28318530717958648f * rintf(t * 0.159154943091895336f);
}

// ---- prep: lay K (f16), W_enc (f16 hi/lo), W_dec (f16) out in frag layout ----
__global__ __launch_bounds__(256) void helix_prep(
    const float* __restrict__ Ks, const float* __restrict__ Wenc,
    const float* __restrict__ Wdec, char* __restrict__ ws)
{
    const int g = blockIdx.x * 256 + threadIdx.x;
    if (g < 32768) {                       // K: [l 4][nt 16][kf 8][ln 64]
        const int ln = g & 63, lg = ln >> 4, lr = ln & 15;
        const int kf = (g >> 6) & 7, nt = (g >> 9) & 15, l = (g >> 13) & 3;
        const float* s = Ks + (((size_t)l * NOSC + nt * 16 + lr) * NOSC + kf * 32 + lg * 8);
        f16x8 o;
        #pragma unroll
        for (int e = 0; e < 8; ++e) o[e] = (f16)s[e];
        *(f16x8*)(ws + (size_t)g * 16) = o;
    } else if (g < 65536) {                // Wenc: [nt 16][kf 16][h 2][ln 64]
        const int q = g - 32768;
        const int ln = q & 63, lg = ln >> 4, lr = ln & 15;
        const int h = (q >> 6) & 1, kf = (q >> 7) & 15, nt = (q >> 11) & 15;
        const float* s = Wenc + ((size_t)(nt * 16 + lr) * NIN + kf * 32 + lg * 8);
        f16x8 o;
        #pragma unroll
        for (int e = 0; e < 8; ++e) {
            float v = s[e];
            f16 hi = (f16)v;
            o[e] = h ? (f16)(v - (float)hi) : hi;
        }
        *(f16x8*)(ws + WS_WENC + (size_t)q * 16) = o;
    } else if (g < 69632) {                // Wdec: [nt 8][kf 8][ln 64]
        const int q = g - 65536;
        const int ln = q & 63, lg = ln >> 4, lr = ln & 15;
        const int kf = (q >> 6) & 7, nt = (q >> 9) & 7;
        const float* s = Wdec + ((size_t)(nt * 16 + lr) * NOSC + kf * 32 + lg * 8);
        f16x8 o;
        #pragma unroll
        for (int e = 0; e < 8; ++e) o[e] = (f16)s[e];
        *(f16x8*)(ws + WS_WD + (size_t)q * 16) = o;
    }
}

__global__ __launch_bounds__(512, 2) void helix13(
    const float* __restrict__ x,
    const float* __restrict__ b_enc,
    const float* __restrict__ omegas,
    const float* __restrict__ Kgl,
    const float* __restrict__ mgl,
    const float* __restrict__ b_dec,
    const char* __restrict__ ws,
    float* __restrict__ out)
{
    // [0,16384): enc-A 16x512 f16 -> dyn dbuf 2x8KB -> decoder A
    // [16384,24576): th_lds f32[8][256]
    // [24576,25088): coherence partials [8 wv][8 r] S,C
    __shared__ __align__(16) char smem[25600];
    float* th_lds = (float*)(smem + 16384);
    float* cohPS  = (float*)(smem + 24576);
    float* cohPC  = (float*)(smem + 24576 + 256);

    const int tid = threadIdx.x;           // 0..511
    const int wv = tid >> 6, ln = tid & 63, lg = ln >> 4, lr = ln & 15;
    const int d  = lr >> 3;
    const int row0 = blockIdx.x * 8;
    const int jb0 = 32 * wv + lr;          // wave owns col-tiles 2wv, 2wv+1
    const int jb1 = jb0 + 16;

    float* out_y   = out;
    float* out_th  = out + (size_t)NB * NOUT;
    float* out_coh = out + (size_t)NB * (NOUT + NOSC);

    const int4 zz = make_int4(0, 0, 0, 0);

    // ---- per-layer constants (static, in regs) ----
    float dtccA[4];
    float2 omL[4];
    #pragma unroll
    for (int l = 0; l < 4; ++l) {
        dtccA[l] = DTT * Kgl[l] * (1.0f / (float)NOSC) * (mgl[l] * 0.5f);
        omL[l] = make_float2(DTT * omegas[l * NOSC + jb0],
                             DTT * omegas[l * NOSC + jb1]);
    }

    // ---- P0: x -> encoder-A LDS, rows m = 2r+h (hi/lo interleaved) ----
    {
        const int r  = wv;                  // 8 rows, one per wave
        const int j0 = ln * 8;              // 8 f32 per thread (one granule)
        const float* xp = x + (size_t)(row0 + r) * NIN + j0;
        float4 v0 = *(const float4*)xp;
        float4 v1 = *(const float4*)(xp + 4);
        float vv[8] = {v0.x, v0.y, v0.z, v0.w, v1.x, v1.y, v1.z, v1.w};
        f16x8 hi, lo;
        #pragma unroll
        for (int e = 0; e < 8; ++e) {
            hi[e] = (f16)vv[e];
            lo[e] = (f16)(vv[e] - (float)hi[e]);
        }
        char* base = smem + (j0 >> 5) * 1024 + ((j0 >> 3) & 3) * 256;
        *(f16x8*)(base + (2 * r) * 16)     = hi;
        *(f16x8*)(base + (2 * r + 1) * 16) = lo;
    }
    __syncthreads();

    // ---- K double-buffer: wave wv owns col-tiles {2wv, 2wv+1} ----
    f16x8 BfA[2][8], BfB[2][8];
    auto loadK = [&](const int l, f16x8 (&B)[2][8]) {
        #pragma unroll
        for (int u = 0; u < 2; ++u) {
            const char* kb = ws + (size_t)l * 131072 + (size_t)(2 * wv + u) * 8192 + ln * 16;
            #pragma unroll
            for (int kf = 0; kf < 8; ++kf)
                B[u][kf] = *(const f16x8*)(kb + kf * 1024);
        }
    };

    // ---- P1: encoder MFMA (full M; hi/lo combine local; 2 tiles/wave) ----
    float th[2][2], sv[2][2], cv[2][2];
    {
        f32x4 accH[2] = {{0,0,0,0},{0,0,0,0}};
        f32x4 accL[2] = {{0,0,0,0},{0,0,0,0}};
        const char* aBase = smem + lg * 256 + lr * 16;
        const char* wE0 = ws + WS_WENC + (size_t)(2 * wv) * 32768 + ln * 16;
        const char* wE1 = wE0 + 32768;
        #pragma unroll 4
        for (int kf = 0; kf < 16; ++kf) {
            f16x8 a   = *(const f16x8*)(aBase + kf * 1024);
            f16x8 bh0 = *(const f16x8*)(wE0 + kf * 2048);
            f16x8 bl0 = *(const f16x8*)(wE0 + kf * 2048 + 1024);
            accH[0] = __builtin_amdgcn_mfma_f32_16x16x32_f16(a, bh0, accH[0], 0, 0, 0);
            accL[0] = __builtin_amdgcn_mfma_f32_16x16x32_f16(a, bl0, accL[0], 0, 0, 0);
            f16x8 bh1 = *(const f16x8*)(wE1 + kf * 2048);
            f16x8 bl1 = *(const f16x8*)(wE1 + kf * 2048 + 1024);
            accH[1] = __builtin_amdgcn_mfma_f32_16x16x32_f16(a, bh1, accH[1], 0, 0, 0);
            accL[1] = __builtin_amdgcn_mfma_f32_16x16x32_f16(a, bl1, accL[1], 0, 0, 0);
        }
        loadK(0, BfA);   // layer-0 K streams under the epilogue + prefill
        #pragma unroll
        for (int u = 0; u < 2; ++u) {
            const float be = b_enc[u ? jb1 : jb0];
            #pragma unroll
            for (int p = 0; p < 2; ++p) {
                float tval = accH[u][2*p] + accH[u][2*p+1]
                           + accL[u][2*p] + accL[u][2*p+1] + be;
                th[u][p] = wrapf(tval);
                __sincosf(th[u][p], &sv[u][p], &cv[u][p]);
            }
        }
    }
    __syncthreads();   // encoder A-reads done before dynamics overwrites

    // ---- dynamics addresses ----
    const int rb = lg * 256 + (lr ^ ((lg & 1) << 1)) * 16;
    int wz[2][4];
    #pragma unroll
    for (int u = 0; u < 2; ++u) {
        const int jbu = u ? jb1 : jb0;
        const int wbase = (jbu >> 5) * 1024 + ((jbu >> 3) & 3) * 256 + (lr & 7) * 2;
        #pragma unroll
        for (int q = 0; q < 4; ++q)
            wz[u][q] = wbase + (((4 * lg + q) ^ (d << 1)) << 4);
    }

    // ---- prefill buf0 with initial S/C ----
    #pragma unroll
    for (int u = 0; u < 2; ++u) {
        *(f16*)(smem + wz[u][0]) = (f16)sv[u][0];
        *(f16*)(smem + wz[u][1]) = (f16)cv[u][0];
        *(f16*)(smem + wz[u][2]) = (f16)sv[u][1];
        *(f16*)(smem + wz[u][3]) = (f16)cv[u][1];
    }
    __syncthreads();

    // ---- dynamics step: 8 reads, 16 MFMA, 4 upds, 8 writes / lane ----
    auto STEP = [&](const char* Sb, char* Wb, const f16x8 (&Bc)[2][8],
                    const float2 om, const float cc) {
        f32x4 aE0 = {0.f,0.f,0.f,0.f}, aO0 = {0.f,0.f,0.f,0.f};
        f32x4 aE1 = {0.f,0.f,0.f,0.f}, aO1 = {0.f,0.f,0.f,0.f};
        __builtin_amdgcn_s_setprio(1);
        #pragma unroll
        for (int kf = 0; kf < 8; kf += 2) {
            f16x8 a0 = *(const f16x8*)(Sb + kf * 1024 + rb);
            f16x8 a1 = *(const f16x8*)(Sb + (kf + 1) * 1024 + rb);
            aE0 = __builtin_amdgcn_mfma_f32_16x16x32_f16(a0, Bc[0][kf],     aE0, 0, 0, 0);
            aE1 = __builtin_amdgcn_mfma_f32_16x16x32_f16(a0, Bc[1][kf],     aE1, 0, 0, 0);
            aO0 = __builtin_amdgcn_mfma_f32_16x16x32_f16(a1, Bc[0][kf + 1], aO0, 0, 0, 0);
            aO1 = __builtin_amdgcn_mfma_f32_16x16x32_f16(a1, Bc[1][kf + 1], aO1, 0, 0, 0);
        }
        f32x4 acc0 = aE0 + aO0;
        f32x4 acc1 = aE1 + aO1;
        #pragma unroll
        for (int p = 0; p < 2; ++p) {
            float diff0 = fmaf(cv[0][p], acc0[2*p], -(sv[0][p] * acc0[2*p+1]));
            th[0][p] += fmaf(diff0, cc, om.x);
            __sincosf(th[0][p], &sv[0][p], &cv[0][p]);
            float diff1 = fmaf(cv[1][p], acc1[2*p], -(sv[1][p] * acc1[2*p+1]));
            th[1][p] += fmaf(diff1, cc, om.y);
            __sincosf(th[1][p], &sv[1][p], &cv[1][p]);
        }
        #pragma unroll
        for (int u = 0; u < 2; ++u) {
            *(f16*)(Wb + wz[u][0]) = (f16)sv[u][0];
            *(f16*)(Wb + wz[u][1]) = (f16)cv[u][0];
            *(f16*)(Wb + wz[u][2]) = (f16)sv[u][1];
            *(f16*)(Wb + wz[u][3]) = (f16)cv[u][1];
        }
        __builtin_amdgcn_s_setprio(0);
        // LDS ops retired; global K prefetch (vmcnt) stays in flight
        asm volatile("s_waitcnt lgkmcnt(0)" ::: "memory");
        __builtin_amdgcn_s_barrier();
    };

    auto runLayer = [&](const f16x8 (&Bc)[2][8], f16x8 (&Bn)[2][8], const int lNext,
                        const float2 om, const float cc) {
        #pragma unroll 1
        for (int p5 = 0; p5 < 5; ++p5) {
            if (p5 == 0 && lNext >= 0) loadK(lNext, Bn);
            STEP(smem,        smem + 8192, Bc, om, cc);
            STEP(smem + 8192, smem,        Bc, om, cc);
        }
    };

    runLayer(BfA, BfB, 1,  omL[0], dtccA[0]);
    runLayer(BfB, BfA, 2,  omL[1], dtccA[1]);
    runLayer(BfA, BfB, 3,  omL[2], dtccA[2]);
    runLayer(BfB, BfA, -1, omL[3], dtccA[3]);

    // ---- epilogue ----
    // wrap; stage th into th_lds (f32) + decoder-A (f16, slot=r, unswizzled)
    #pragma unroll
    for (int u = 0; u < 2; ++u) {
        const int jbu = u ? jb1 : jb0;
        const int dbase = (jbu >> 5) * 1024 + ((jbu >> 3) & 3) * 256 + (lr & 7) * 2;
        #pragma unroll
        for (int p = 0; p < 2; ++p) {
            const float wt = wrapf(th[u][p]);
            th_lds[(2 * lg + p) * NOSC + jbu] = wt;
            *(f16*)(smem + dbase + (2 * lg + p) * 16) = (f16)wt;
        }
    }
    #pragma unroll
    for (int p = 0; p < 2; ++p) {
        float pS = sv[0][p] + sv[1][p];
        float pC = cv[0][p] + cv[1][p];
        pS += __shfl_xor(pS, 1); pC += __shfl_xor(pC, 1);
        pS += __shfl_xor(pS, 2); pC += __shfl_xor(pC, 2);
        pS += __shfl_xor(pS, 4); pC += __shfl_xor(pC, 4);
        pS += __shfl_xor(pS, 8); pC += __shfl_xor(pC, 8);
        if (lr == 0) {
            cohPS[wv * 8 + 2 * lg + p] = pS;
            cohPC[wv * 8 + 2 * lg + p] = pC;
        }
    }
    __syncthreads();

    if (tid < 8)   // zero granule per kf (slot 8, gcol 0) for decoder rows 8-15
        *(int4*)(smem + tid * 1024 + 128) = zz;
    {              // theta out, coalesced: 512 threads x float4 = 8x256
        float4 v = ((const float4*)th_lds)[tid];
        *(float4*)(out_th + (size_t)row0 * NOSC + tid * 4) = v;
    }
    if (tid < 8) { // coherence
        float S = 0.f, C = 0.f;
        #pragma unroll
        for (int w2 = 0; w2 < 8; ++w2) {
            S += cohPS[w2 * 8 + tid];
            C += cohPC[w2 * 8 + tid];
        }
        S *= (1.0f / (float)NOSC);
        C *= (1.0f / (float)NOSC);
        out_coh[row0 + tid] = sqrtf(S * S + C * C);
    }
    __syncthreads();

    // decoder MFMA: wave wv -> out col-tile wv; rows 8-15 broadcast-zero
    {
        const int rbD = (lr < 8) ? (lg * 256 + lr * 16) : 128;
        f32x4 aD = {0.f, 0.f, 0.f, 0.f};
        #pragma unroll
        for (int kf = 0; kf < 8; ++kf) {
            f16x8 a  = *(const f16x8*)(smem + kf * 1024 + rbD);
            f16x8 bw = *(const f16x8*)(ws + WS_WD + (size_t)wv * 8192 + kf * 1024 + ln * 16);
            aD = __builtin_amdgcn_mfma_f32_16x16x32_f16(a, bw, aD, 0, 0, 0);
        }
        if (lg < 2) {
            const int col = 16 * wv + lr;
            const float bd = b_dec[col];
            #pragma unroll
            for (int e = 0; e < 4; ++e)
                out_y[(size_t)(row0 + 4 * lg + e) * NOUT + col] = aD[e] + bd;
        }
    }
}

extern "C" void kernel_launch(void* const* d_in, const int* in_sizes, int n_in,
                              void* d_out, int out_size, void* d_ws, size_t ws_size,
                              hipStream_t stream) {
    const float* x     = (const float*)d_in[0];
    const float* W_enc = (const float*)d_in[1];
    const float* b_enc = (const float*)d_in[2];
    const float* Ks    = (const float*)d_in[3];
    const float* omg   = (const float*)d_in[4];
    const float* Kgl   = (const float*)d_in[5];
    const float* mgl   = (const float*)d_in[6];
    const float* W_dec = (const float*)d_in[7];
    const float* b_dec = (const float*)d_in[8];
    char* ws = (char*)d_ws;

    helix_prep<<<272, 256, 0, stream>>>(Ks, W_enc, W_dec, ws);
    helix13<<<NB / 8, 512, 0, stream>>>(x, b_enc, omg, Kgl, mgl, b_dec, ws, (float*)d_out);
}

// Round 13
// 42.441 us; speedup vs baseline: 1.0771x; 1.0771x over previous
//
#include <hip/hip_runtime.h>

// Kuramoto helix network v14 = v11 skeleton + non-dynamics trims.
// v13 post-mortem: dynamics IS LDS-pipe-floor-bound at 16 waves (128KB/step
// @ 85B/cyc = 1536cyc; measured 1680). v13's 8-wave variant lost more to
// exposed latency than it saved in reads. Keep v11's decomposition; reclaim
// the other ~14us: encoder 2-deep W prefetch (L2-BW floor), W_dec frags
// prefetched to regs during layer 3 (decoder = pure MFMA), STEP tail
// reordered (diffs -> th -> sincos/write interleave).

#define NB 2048
#define NIN 512
#define NOUT 128
#define NOSC 256
#define DTT 0.1f

#define WS_WENC (512*1024)
#define WS_WD   (1024*1024)

typedef _Float16 f16;
typedef _Float16 f16x4 __attribute__((ext_vector_type(4)));
typedef _Float16 f16x8 __attribute__((ext_vector_type(8)));
typedef float f32x4 __attribute__((ext_vector_type(4)));

__device__ __forceinline__ float wrapf(float t) {
    return t - 6.28318530717958648f * rintf(t * 0.159154943091895336f);
}

// ---- prep: lay K (f16), W_enc (f16 hi/lo), W_dec (f16) out in frag layout ----
__global__ __launch_bounds__(256) void helix_prep(
    const float* __restrict__ Ks, const float* __restrict__ Wenc,
    const float* __restrict__ Wdec, char* __restrict__ ws)
{
    const int g = blockIdx.x * 256 + threadIdx.x;
    if (g < 32768) {                       // K: [l 4][nt 16][kf 8][ln 64]
        const int ln = g & 63, lg = ln >> 4, lr = ln & 15;
        const int kf = (g >> 6) & 7, nt = (g >> 9) & 15, l = (g >> 13) & 3;
        const float* s = Ks + (((size_t)l * NOSC + nt * 16 + lr) * NOSC + kf * 32 + lg * 8);
        f16x8 o;
        #pragma unroll
        for (int e = 0; e < 8; ++e) o[e] = (f16)s[e];
        *(f16x8*)(ws + (size_t)g * 16) = o;
    } else if (g < 65536) {                // Wenc: [nt 16][kf 16][h 2][ln 64]
        const int q = g - 32768;
        const int ln = q & 63, lg = ln >> 4, lr = ln & 15;
        const int h = (q >> 6) & 1, kf = (q >> 7) & 15, nt = (q >> 11) & 15;
        const float* s = Wenc + ((size_t)(nt * 16 + lr) * NIN + kf * 32 + lg * 8);
        f16x8 o;
        #pragma unroll
        for (int e = 0; e < 8; ++e) {
            float v = s[e];
            f16 hi = (f16)v;
            o[e] = h ? (f16)(v - (float)hi) : hi;
        }
        *(f16x8*)(ws + WS_WENC + (size_t)q * 16) = o;
    } else if (g < 69632) {                // Wdec: [nt 8][kf 8][ln 64]
        const int q = g - 65536;
        const int ln = q & 63, lg = ln >> 4, lr = ln & 15;
        const int kf = (q >> 6) & 7, nt = (q >> 9) & 7;
        const float* s = Wdec + ((size_t)(nt * 16 + lr) * NOSC + kf * 32 + lg * 8);
        f16x8 o;
        #pragma unroll
        for (int e = 0; e < 8; ++e) o[e] = (f16)s[e];
        *(f16x8*)(ws + WS_WD + (size_t)q * 16) = o;
    }
}

__global__ __launch_bounds__(1024, 4) void helix14(
    const float* __restrict__ x,
    const float* __restrict__ b_enc,
    const float* __restrict__ omegas,
    const float* __restrict__ Kgl,
    const float* __restrict__ mgl,
    const float* __restrict__ b_dec,
    const char* __restrict__ ws,
    float* __restrict__ out)
{
    __shared__ __align__(16) char smem[25600];
    float* th_lds = (float*)(smem + 16384);
    float* cohPS  = (float*)(smem + 24576);           // [16 wv][8 r]
    float* cohPC  = (float*)(smem + 25088);

    const int tid = threadIdx.x;           // 0..1023
    const int wv = tid >> 6, ln = tid & 63, lg = ln >> 4, lr = ln & 15;
    const int d  = lr >> 3;
    const int row0 = blockIdx.x * 8;
    const int jb  = 16 * wv + lr;          // this lane's oscillator column

    float* out_y   = out;
    float* out_th  = out + (size_t)NB * NOUT;
    float* out_coh = out + (size_t)NB * (NOUT + NOSC);

    const int4 zz = make_int4(0, 0, 0, 0);

    // ---- per-layer constants (all static, held in regs) ----
    float dtccA[4], omL[4];
    #pragma unroll
    for (int l = 0; l < 4; ++l) {
        dtccA[l] = DTT * Kgl[l] * (1.0f / (float)NOSC) * (mgl[l] * 0.5f);
        omL[l]   = DTT * omegas[l * NOSC + jb];
    }

    // ---- P0: x -> encoder-A LDS, rows m = 2r+h (hi/lo interleaved) ----
    {
        const int r  = tid >> 7;            // 0..7
        const int j0 = (tid & 127) << 2;    // 4 f32 per thread
        float4 v = *(const float4*)(x + (size_t)(row0 + r) * NIN + j0);
        float vv[4] = {v.x, v.y, v.z, v.w};
        f16x4 hi, lo;
        #pragma unroll
        for (int e = 0; e < 4; ++e) {
            hi[e] = (f16)vv[e];
            lo[e] = (f16)(vv[e] - (float)hi[e]);
        }
        char* base = smem + (j0 >> 5) * 1024 + ((j0 >> 3) & 3) * 256 + (j0 & 7) * 2;
        *(f16x4*)(base + (2 * r) * 16)     = hi;
        *(f16x4*)(base + (2 * r + 1) * 16) = lo;
    }
    __syncthreads();

    // ---- K loader: wave wv owns col-tile wv ----
    f16x8 Bf[8];
    auto loadK = [&](const int l) {
        const char* kb = ws + (size_t)l * 131072 + (size_t)wv * 8192 + ln * 16;
        #pragma unroll
        for (int kf = 0; kf < 8; ++kf)
            Bf[kf] = *(const f16x8*)(kb + kf * 1024);
    };

    // ---- P1: encoder MFMA (full M; 2-deep weight prefetch) ----
    float th[2], sv[2], cv[2];
    {
        f32x4 accH = {0,0,0,0}, accL = {0,0,0,0};
        const char* aBase = smem + lg * 256 + lr * 16;
        const char* wE = ws + WS_WENC + (size_t)wv * 32768 + ln * 16;
        f16x8 bh = *(const f16x8*)(wE);
        f16x8 bl = *(const f16x8*)(wE + 1024);
        #pragma unroll
        for (int kf = 0; kf < 16; ++kf) {
            const int kn = (kf < 15) ? (kf + 1) : 15;
            f16x8 bh_n = *(const f16x8*)(wE + kn * 2048);
            f16x8 bl_n = *(const f16x8*)(wE + kn * 2048 + 1024);
            f16x8 a = *(const f16x8*)(aBase + kf * 1024);
            accH = __builtin_amdgcn_mfma_f32_16x16x32_f16(a, bh, accH, 0, 0, 0);
            accL = __builtin_amdgcn_mfma_f32_16x16x32_f16(a, bl, accL, 0, 0, 0);
            bh = bh_n;
            bl = bl_n;
        }
        loadK(0);   // layer-0 K streams under the epilogue + prefill
        const float be = b_enc[jb];
        #pragma unroll
        for (int p = 0; p < 2; ++p) {
            float tval = accH[2*p] + accH[2*p+1] + accL[2*p] + accL[2*p+1] + be;
            th[p] = wrapf(tval);
            __sincosf(th[p], &sv[p], &cv[p]);
        }
    }
    __syncthreads();   // all encoder A-reads done before dynamics overwrites

    // ---- dynamics addresses ----
    const int rb = lg * 256 + (lr ^ ((lg & 1) << 1)) * 16;
    const int wbase = (jb >> 5) * 1024 + ((jb >> 3) & 3) * 256 + (lr & 7) * 2;
    const int wz0 = wbase + (((4 * lg + 0) ^ (d << 1)) << 4);
    const int wz1 = wbase + (((4 * lg + 1) ^ (d << 1)) << 4);
    const int wz2 = wbase + (((4 * lg + 2) ^ (d << 1)) << 4);
    const int wz3 = wbase + (((4 * lg + 3) ^ (d << 1)) << 4);

    // ---- prefill buf0 with initial S/C ----
    *(f16*)(smem + wz0) = (f16)sv[0];
    *(f16*)(smem + wz1) = (f16)cv[0];
    *(f16*)(smem + wz2) = (f16)sv[1];
    *(f16*)(smem + wz3) = (f16)cv[1];
    __syncthreads();

    // ---- dynamics step: 8 reads, 8 MFMA, short tail, 4 writes ----
    auto STEP = [&](const char* Sb, char* Wb, const float om, const float cc) {
        f32x4 acc = {0.f, 0.f, 0.f, 0.f};
        __builtin_amdgcn_s_setprio(1);
        #pragma unroll
        for (int kf = 0; kf < 8; ++kf) {
            f16x8 a = *(const f16x8*)(Sb + kf * 1024 + rb);
            acc = __builtin_amdgcn_mfma_f32_16x16x32_f16(a, Bf[kf], acc, 0, 0, 0);
        }
        // tail: both diffs first (old s/c), then th, then sincos/write interleave
        float diff0 = fmaf(cv[0], acc[0], -(sv[0] * acc[1]));
        float diff1 = fmaf(cv[1], acc[2], -(sv[1] * acc[3]));
        th[0] += fmaf(diff0, cc, om);
        th[1] += fmaf(diff1, cc, om);
        __sincosf(th[0], &sv[0], &cv[0]);
        *(f16*)(Wb + wz0) = (f16)sv[0];
        *(f16*)(Wb + wz1) = (f16)cv[0];
        __sincosf(th[1], &sv[1], &cv[1]);
        *(f16*)(Wb + wz2) = (f16)sv[1];
        *(f16*)(Wb + wz3) = (f16)cv[1];
        __builtin_amdgcn_s_setprio(0);
        __syncthreads();
    };

    auto runLayer = [&](const float om, const float cc) {
        #pragma unroll 1
        for (int p5 = 0; p5 < 5; ++p5) {
            STEP(smem,        smem + 8192, om, cc);
            STEP(smem + 8192, smem,        om, cc);
        }
    };

    f16x8 bwD[8];   // decoder weight frags, prefetched during layer 3

    runLayer(omL[0], dtccA[0]);
    loadK(1); runLayer(omL[1], dtccA[1]);
    loadK(2); runLayer(omL[2], dtccA[2]);
    loadK(3);
    {
        const char* wd = ws + WS_WD + (size_t)(wv & 7) * 8192 + ln * 16;
        #pragma unroll
        for (int kf = 0; kf < 8; ++kf)
            bwD[kf] = *(const f16x8*)(wd + kf * 1024);
    }
    runLayer(omL[3], dtccA[3]);

    // ---- epilogue ----
    // wrap; stage th into th_lds (f32) + decoder-A (f16, slot=r, unswizzled)
    {
        const int dbase = (jb >> 5) * 1024 + ((jb >> 3) & 3) * 256 + (lr & 7) * 2;
        #pragma unroll
        for (int p = 0; p < 2; ++p) {
            const float wt = wrapf(th[p]);
            th_lds[(2 * lg + p) * NOSC + jb] = wt;
            *(f16*)(smem + dbase + (2 * lg + p) * 16) = (f16)wt;
        }
    }
    // coherence partials: reduce over lr within each lg group
    #pragma unroll
    for (int p = 0; p < 2; ++p) {
        float pS = sv[p], pC = cv[p];
        pS += __shfl_xor(pS, 1); pC += __shfl_xor(pC, 1);
        pS += __shfl_xor(pS, 2); pC += __shfl_xor(pC, 2);
        pS += __shfl_xor(pS, 4); pC += __shfl_xor(pC, 4);
        pS += __shfl_xor(pS, 8); pC += __shfl_xor(pC, 8);
        if (lr == 0) {
            cohPS[wv * 8 + 2 * lg + p] = pS;
            cohPC[wv * 8 + 2 * lg + p] = pC;
        }
    }
    __syncthreads();

    if (tid < 8)   // zero granule (slot 8, gcol 0) per kf for decoder rows 8-15
        *(int4*)(smem + tid * 1024 + 128) = zz;
    if (tid < 512) {   // theta out, coalesced (8 rows x 256 contiguous)
        float4 v = ((const float4*)th_lds)[tid];
        *(float4*)(out_th + (size_t)row0 * NOSC + tid * 4) = v;
    }
    if (tid < 8) {     // coherence
        float S = 0.f, C = 0.f;
        #pragma unroll
        for (int w2 = 0; w2 < 16; ++w2) {
            S += cohPS[w2 * 8 + tid];
            C += cohPC[w2 * 8 + tid];
        }
        S *= (1.0f / (float)NOSC);
        C *= (1.0f / (float)NOSC);
        out_coh[row0 + tid] = sqrtf(S * S + C * C);
    }
    __syncthreads();

    // decoder MFMA (pure compute, weights already in regs): waves 0-7
    if (wv < 8) {
        const int rbD = (lr < 8) ? (lg * 256 + lr * 16) : 128;
        f32x4 aD = {0.f, 0.f, 0.f, 0.f};
        #pragma unroll
        for (int kf = 0; kf < 8; ++kf) {
            f16x8 a = *(const f16x8*)(smem + kf * 1024 + rbD);
            aD = __builtin_amdgcn_mfma_f32_16x16x32_f16(a, bwD[kf], aD, 0, 0, 0);
        }
        if (lg < 2) {
            const int col = 16 * wv + lr;
            const float bd = b_dec[col];
            #pragma unroll
            for (int e = 0; e < 4; ++e)
                out_y[(size_t)(row0 + 4 * lg + e) * NOUT + col] = aD[e] + bd;
        }
    }
}

extern "C" void kernel_launch(void* const* d_in, const int* in_sizes, int n_in,
                              void* d_out, int out_size, void* d_ws, size_t ws_size,
                              hipStream_t stream) {
    const float* x     = (const float*)d_in[0];
    const float* W_enc = (const float*)d_in[1];
    const float* b_enc = (const float*)d_in[2];
    const float* Ks    = (const float*)d_in[3];
    const float* omg   = (const float*)d_in[4];
    const float* Kgl   = (const float*)d_in[5];
    const float* mgl   = (const float*)d_in[6];
    const float* W_dec = (const float*)d_in[7];
    const float* b_dec = (const float*)d_in[8];
    char* ws = (char*)d_ws;

    helix_prep<<<272, 256, 0, stream>>>(Ks, W_enc, W_dec, ws);
    helix14<<<NB / 8, 1024, 0, stream>>>(x, b_enc, omg, Kgl, mgl, b_dec, ws, (float*)d_out);
}

// Round 14
// 42.079 us; speedup vs baseline: 1.0863x; 1.0086x over previous
//
#include <hip/hip_runtime.h>

// Kuramoto helix network v15 = v14 + forced K-prefetch across layer bounds.
//  - STEP barrier: s_waitcnt lgkmcnt(0) + s_barrier (no vmcnt drain) so
//    global K loads stay in flight across step barriers.
//  - K reg double-buffer; loadK(l+1) issued at double-step 1 of layer l;
//    asm keep-alive pin at layer end forces materialization + vmcnt wait
//    BEFORE the boundary (v12's attempt was sunk by the compiler: VGPR=64).
//  - v14's other trims kept: 2-deep encoder weight prefetch, bwD prefetch
//    during layer 3, short STEP tail.

#define NB 2048
#define NIN 512
#define NOUT 128
#define NOSC 256
#define DTT 0.1f

#define WS_WENC (512*1024)
#define WS_WD   (1024*1024)

typedef _Float16 f16;
typedef _Float16 f16x4 __attribute__((ext_vector_type(4)));
typedef _Float16 f16x8 __attribute__((ext_vector_type(8)));
typedef float f32x4 __attribute__((ext_vector_type(4)));

__device__ __forceinline__ float wrapf(float t) {
    return t - 6.28318530717958648f * rintf(t * 0.159154943091895336f);
}

// ---- prep: lay K (f16), W_enc (f16 hi/lo), W_dec (f16) out in frag layout ----
__global__ __launch_bounds__(256) void helix_prep(
    const float* __restrict__ Ks, const float* __restrict__ Wenc,
    const float* __restrict__ Wdec, char* __restrict__ ws)
{
    const int g = blockIdx.x * 256 + threadIdx.x;
    if (g < 32768) {                       // K: [l 4][nt 16][kf 8][ln 64]
        const int ln = g & 63, lg = ln >> 4, lr = ln & 15;
        const int kf = (g >> 6) & 7, nt = (g >> 9) & 15, l = (g >> 13) & 3;
        const float* s = Ks + (((size_t)l * NOSC + nt * 16 + lr) * NOSC + kf * 32 + lg * 8);
        f16x8 o;
        #pragma unroll
        for (int e = 0; e < 8; ++e) o[e] = (f16)s[e];
        *(f16x8*)(ws + (size_t)g * 16) = o;
    } else if (g < 65536) {                // Wenc: [nt 16][kf 16][h 2][ln 64]
        const int q = g - 32768;
        const int ln = q & 63, lg = ln >> 4, lr = ln & 15;
        const int h = (q >> 6) & 1, kf = (q >> 7) & 15, nt = (q >> 11) & 15;
        const float* s = Wenc + ((size_t)(nt * 16 + lr) * NIN + kf * 32 + lg * 8);
        f16x8 o;
        #pragma unroll
        for (int e = 0; e < 8; ++e) {
            float v = s[e];
            f16 hi = (f16)v;
            o[e] = h ? (f16)(v - (float)hi) : hi;
        }
        *(f16x8*)(ws + WS_WENC + (size_t)q * 16) = o;
    } else if (g < 69632) {                // Wdec: [nt 8][kf 8][ln 64]
        const int q = g - 65536;
        const int ln = q & 63, lg = ln >> 4, lr = ln & 15;
        const int kf = (q >> 6) & 7, nt = (q >> 9) & 7;
        const float* s = Wdec + ((size_t)(nt * 16 + lr) * NOSC + kf * 32 + lg * 8);
        f16x8 o;
        #pragma unroll
        for (int e = 0; e < 8; ++e) o[e] = (f16)s[e];
        *(f16x8*)(ws + WS_WD + (size_t)q * 16) = o;
    }
}

__global__ __launch_bounds__(1024, 4) void helix15(
    const float* __restrict__ x,
    const float* __restrict__ b_enc,
    const float* __restrict__ omegas,
    const float* __restrict__ Kgl,
    const float* __restrict__ mgl,
    const float* __restrict__ b_dec,
    const char* __restrict__ ws,
    float* __restrict__ out)
{
    __shared__ __align__(16) char smem[25600];
    float* th_lds = (float*)(smem + 16384);
    float* cohPS  = (float*)(smem + 24576);           // [16 wv][8 r]
    float* cohPC  = (float*)(smem + 25088);

    const int tid = threadIdx.x;           // 0..1023
    const int wv = tid >> 6, ln = tid & 63, lg = ln >> 4, lr = ln & 15;
    const int d  = lr >> 3;
    const int row0 = blockIdx.x * 8;
    const int jb  = 16 * wv + lr;          // this lane's oscillator column

    float* out_y   = out;
    float* out_th  = out + (size_t)NB * NOUT;
    float* out_coh = out + (size_t)NB * (NOUT + NOSC);

    const int4 zz = make_int4(0, 0, 0, 0);

    // ---- per-layer constants (all static, held in regs) ----
    float dtccA[4], omL[4];
    #pragma unroll
    for (int l = 0; l < 4; ++l) {
        dtccA[l] = DTT * Kgl[l] * (1.0f / (float)NOSC) * (mgl[l] * 0.5f);
        omL[l]   = DTT * omegas[l * NOSC + jb];
    }

    // ---- P0: x -> encoder-A LDS, rows m = 2r+h (hi/lo interleaved) ----
    {
        const int r  = tid >> 7;            // 0..7
        const int j0 = (tid & 127) << 2;    // 4 f32 per thread
        float4 v = *(const float4*)(x + (size_t)(row0 + r) * NIN + j0);
        float vv[4] = {v.x, v.y, v.z, v.w};
        f16x4 hi, lo;
        #pragma unroll
        for (int e = 0; e < 4; ++e) {
            hi[e] = (f16)vv[e];
            lo[e] = (f16)(vv[e] - (float)hi[e]);
        }
        char* base = smem + (j0 >> 5) * 1024 + ((j0 >> 3) & 3) * 256 + (j0 & 7) * 2;
        *(f16x4*)(base + (2 * r) * 16)     = hi;
        *(f16x4*)(base + (2 * r + 1) * 16) = lo;
    }
    __syncthreads();

    // ---- K loader (double-buffered): wave wv owns col-tile wv ----
    f16x8 BfA[8], BfB[8];
    auto loadK = [&](const int l, f16x8 (&B)[8]) {
        const char* kb = ws + (size_t)l * 131072 + (size_t)wv * 8192 + ln * 16;
        #pragma unroll
        for (int kf = 0; kf < 8; ++kf)
            B[kf] = *(const f16x8*)(kb + kf * 1024);
    };

    // ---- P1: encoder MFMA (full M; 2-deep weight prefetch) ----
    float th[2], sv[2], cv[2];
    {
        f32x4 accH = {0,0,0,0}, accL = {0,0,0,0};
        const char* aBase = smem + lg * 256 + lr * 16;
        const char* wE = ws + WS_WENC + (size_t)wv * 32768 + ln * 16;
        f16x8 bh = *(const f16x8*)(wE);
        f16x8 bl = *(const f16x8*)(wE + 1024);
        #pragma unroll
        for (int kf = 0; kf < 16; ++kf) {
            const int kn = (kf < 15) ? (kf + 1) : 15;
            f16x8 bh_n = *(const f16x8*)(wE + kn * 2048);
            f16x8 bl_n = *(const f16x8*)(wE + kn * 2048 + 1024);
            f16x8 a = *(const f16x8*)(aBase + kf * 1024);
            accH = __builtin_amdgcn_mfma_f32_16x16x32_f16(a, bh, accH, 0, 0, 0);
            accL = __builtin_amdgcn_mfma_f32_16x16x32_f16(a, bl, accL, 0, 0, 0);
            bh = bh_n;
            bl = bl_n;
        }
        loadK(0, BfA);   // layer-0 K streams under the epilogue + prefill
        const float be = b_enc[jb];
        #pragma unroll
        for (int p = 0; p < 2; ++p) {
            float tval = accH[2*p] + accH[2*p+1] + accL[2*p] + accL[2*p+1] + be;
            th[p] = wrapf(tval);
            __sincosf(th[p], &sv[p], &cv[p]);
        }
    }
    __syncthreads();   // all encoder A-reads done before dynamics overwrites

    // ---- dynamics addresses ----
    const int rb = lg * 256 + (lr ^ ((lg & 1) << 1)) * 16;
    const int wbase = (jb >> 5) * 1024 + ((jb >> 3) & 3) * 256 + (lr & 7) * 2;
    const int wz0 = wbase + (((4 * lg + 0) ^ (d << 1)) << 4);
    const int wz1 = wbase + (((4 * lg + 1) ^ (d << 1)) << 4);
    const int wz2 = wbase + (((4 * lg + 2) ^ (d << 1)) << 4);
    const int wz3 = wbase + (((4 * lg + 3) ^ (d << 1)) << 4);

    // ---- prefill buf0 with initial S/C ----
    *(f16*)(smem + wz0) = (f16)sv[0];
    *(f16*)(smem + wz1) = (f16)cv[0];
    *(f16*)(smem + wz2) = (f16)sv[1];
    *(f16*)(smem + wz3) = (f16)cv[1];
    __syncthreads();

    // ---- dynamics step: 8 reads, 8 MFMA, short tail, 4 writes ----
    // raw barrier: LDS drained, global (K prefetch) stays in flight
    auto STEP = [&](const char* Sb, char* Wb, const f16x8 (&Bc)[8],
                    const float om, const float cc) {
        f32x4 acc = {0.f, 0.f, 0.f, 0.f};
        __builtin_amdgcn_s_setprio(1);
        #pragma unroll
        for (int kf = 0; kf < 8; ++kf) {
            f16x8 a = *(const f16x8*)(Sb + kf * 1024 + rb);
            acc = __builtin_amdgcn_mfma_f32_16x16x32_f16(a, Bc[kf], acc, 0, 0, 0);
        }
        float diff0 = fmaf(cv[0], acc[0], -(sv[0] * acc[1]));
        float diff1 = fmaf(cv[1], acc[2], -(sv[1] * acc[3]));
        th[0] += fmaf(diff0, cc, om);
        th[1] += fmaf(diff1, cc, om);
        __sincosf(th[0], &sv[0], &cv[0]);
        *(f16*)(Wb + wz0) = (f16)sv[0];
        *(f16*)(Wb + wz1) = (f16)cv[0];
        __sincosf(th[1], &sv[1], &cv[1]);
        *(f16*)(Wb + wz2) = (f16)sv[1];
        *(f16*)(Wb + wz3) = (f16)cv[1];
        __builtin_amdgcn_s_setprio(0);
        asm volatile("s_waitcnt lgkmcnt(0)" ::: "memory");
        __builtin_amdgcn_s_barrier();
    };

    // layer runner: issue next-layer K mid-layer; pin (and thereby wait) at
    // layer end so the boundary itself costs ~0.
    auto runLayer = [&](const f16x8 (&Bc)[8], f16x8 (&Bn)[8], const int lNext,
                        const float om, const float cc) {
        #pragma unroll 1
        for (int p5 = 0; p5 < 5; ++p5) {
            if (p5 == 1 && lNext >= 0) loadK(lNext, Bn);
            STEP(smem,        smem + 8192, Bc, om, cc);
            STEP(smem + 8192, smem,        Bc, om, cc);
        }
        if (lNext >= 0) {
            #pragma unroll
            for (int kf = 0; kf < 8; ++kf)
                asm volatile("" : : "v"(Bn[kf]));   // force materialize + wait here
        }
    };

    f16x8 bwD[8];   // decoder weight frags, prefetched during layer 3

    runLayer(BfA, BfB, 1, omL[0], dtccA[0]);
    runLayer(BfB, BfA, 2, omL[1], dtccA[1]);
    runLayer(BfA, BfB, 3, omL[2], dtccA[2]);
    {
        const char* wd = ws + WS_WD + (size_t)(wv & 7) * 8192 + ln * 16;
        #pragma unroll
        for (int kf = 0; kf < 8; ++kf)
            bwD[kf] = *(const f16x8*)(wd + kf * 1024);
    }
    runLayer(BfB, BfA, -1, omL[3], dtccA[3]);

    // ---- epilogue ----
    // wrap; stage th into th_lds (f32) + decoder-A (f16, slots 0-7)
    {
        const int dbase = (jb >> 5) * 1024 + ((jb >> 3) & 3) * 256 + (lr & 7) * 2;
        #pragma unroll
        for (int p = 0; p < 2; ++p) {
            const float wt = wrapf(th[p]);
            th_lds[(2 * lg + p) * NOSC + jb] = wt;
            *(f16*)(smem + dbase + (2 * lg + p) * 16) = (f16)wt;
        }
    }
    // coherence partials: reduce over lr within each lg group
    #pragma unroll
    for (int p = 0; p < 2; ++p) {
        float pS = sv[p], pC = cv[p];
        pS += __shfl_xor(pS, 1); pC += __shfl_xor(pC, 1);
        pS += __shfl_xor(pS, 2); pC += __shfl_xor(pC, 2);
        pS += __shfl_xor(pS, 4); pC += __shfl_xor(pC, 4);
        pS += __shfl_xor(pS, 8); pC += __shfl_xor(pC, 8);
        if (lr == 0) {
            cohPS[wv * 8 + 2 * lg + p] = pS;
            cohPC[wv * 8 + 2 * lg + p] = pC;
        }
    }
    __syncthreads();

    if (tid < 8)   // zero granule (slot 8, gcol 0) per kf for decoder rows 8-15
        *(int4*)(smem + tid * 1024 + 128) = zz;
    if (tid < 512) {   // theta out, coalesced (8 rows x 256 contiguous)
        float4 v = ((const float4*)th_lds)[tid];
        *(float4*)(out_th + (size_t)row0 * NOSC + tid * 4) = v;
    }
    if (tid < 8) {     // coherence
        float S = 0.f, C = 0.f;
        #pragma unroll
        for (int w2 = 0; w2 < 16; ++w2) {
            S += cohPS[w2 * 8 + tid];
            C += cohPC[w2 * 8 + tid];
        }
        S *= (1.0f / (float)NOSC);
        C *= (1.0f / (float)NOSC);
        out_coh[row0 + tid] = sqrtf(S * S + C * C);
    }
    __syncthreads();

    // decoder MFMA (pure compute, weights already in regs): waves 0-7
    if (wv < 8) {
        const int rbD = (lr < 8) ? (lg * 256 + lr * 16) : 128;
        f32x4 aD = {0.f, 0.f, 0.f, 0.f};
        #pragma unroll
        for (int kf = 0; kf < 8; ++kf) {
            f16x8 a = *(const f16x8*)(smem + kf * 1024 + rbD);
            aD = __builtin_amdgcn_mfma_f32_16x16x32_f16(a, bwD[kf], aD, 0, 0, 0);
        }
        if (lg < 2) {
            const int col = 16 * wv + lr;
            const float bd = b_dec[col];
            #pragma unroll
            for (int e = 0; e < 4; ++e)
                out_y[(size_t)(row0 + 4 * lg + e) * NOUT + col] = aD[e] + bd;
        }
    }
}

extern "C" void kernel_launch(void* const* d_in, const int* in_sizes, int n_in,
                              void* d_out, int out_size, void* d_ws, size_t ws_size,
                              hipStream_t stream) {
    const float* x     = (const float*)d_in[0];
    const float* W_enc = (const float*)d_in[1];
    const float* b_enc = (const float*)d_in[2];
    const float* Ks    = (const float*)d_in[3];
    const float* omg   = (const float*)d_in[4];
    const float* Kgl   = (const float*)d_in[5];
    const float* mgl   = (const float*)d_in[6];
    const float* W_dec = (const float*)d_in[7];
    const float* b_dec = (const float*)d_in[8];
    char* ws = (char*)d_ws;

    helix_prep<<<272, 256, 0, stream>>>(Ks, W_enc, W_dec, ws);
    helix15<<<NB / 8, 1024, 0, stream>>>(x, b_enc, omg, Kgl, mgl, b_dec, ws, (float*)d_out);
}